// Round 3
// baseline (73.918 us; speedup 1.0000x reference)
//
#include <hip/hip_runtime.h>
#include <math.h>

constexpr int Bn = 1024, Vn = 5023;
constexpr int NB = 16;            // batches per block in the main kernel
constexpr int PARAM_STRIDE = 96;  // 36 pose_feat + 5*12 A per batch

// Pin a float in a VGPR: compiler cannot rematerialize/sink the producing
// load past this point (guide rule #17).
#define PIN(x) asm volatile("" : "+v"(x))

// ---------------------------------------------------------------------------
// Kernel A: per-batch pose math. 1 thread per batch.
// params layout per batch: [0..35] pose_feat (joint-1..4, row-major 3x3 - I),
//                          [36..95] A_j as 3x4 row-major, j=0..4
// ---------------------------------------------------------------------------

__device__ inline void rodrigues3(float rx, float ry, float rz, float R[9]) {
    const float eps = 1e-8f;
    float ax = rx + eps, ay = ry + eps, az = rz + eps;
    float ang = sqrtf(ax * ax + ay * ay + az * az);
    float inv = 1.0f / ang;
    float dx = rx * inv, dy = ry * inv, dz = rz * inv;
    float s = sinf(ang), c = cosf(ang), omc = 1.0f - c;
    float K[9] = {0.f, -dz, dy, dz, 0.f, -dx, -dy, dx, 0.f};
    float K2[9];
#pragma unroll
    for (int r = 0; r < 3; r++)
#pragma unroll
        for (int k = 0; k < 3; k++) {
            float acc = 0.f;
#pragma unroll
            for (int i = 0; i < 3; i++) acc += K[r * 3 + i] * K[i * 3 + k];
            K2[r * 3 + k] = acc;
        }
#pragma unroll
    for (int i = 0; i < 9; i++) R[i] = s * K[i] + omc * K2[i];
    R[0] += 1.f; R[4] += 1.f; R[8] += 1.f;
}

__device__ inline void rot6d(const float* x, float R[9]) {
    float a1x = x[0], a1y = x[1], a1z = x[2];
    float a2x = x[3], a2y = x[4], a2z = x[5];
    float n1 = sqrtf(a1x * a1x + a1y * a1y + a1z * a1z);
    float b1x = a1x / n1, b1y = a1y / n1, b1z = a1z / n1;
    float d = b1x * a2x + b1y * a2y + b1z * a2z;
    float tx = a2x - d * b1x, ty = a2y - d * b1y, tz = a2z - d * b1z;
    float n2 = sqrtf(tx * tx + ty * ty + tz * tz);
    float b2x = tx / n2, b2y = ty / n2, b2z = tz / n2;
    float b3x = b1y * b2z - b1z * b2y;
    float b3y = b1z * b2x - b1x * b2z;
    float b3z = b1x * b2y - b1y * b2x;
    R[0] = b1x; R[1] = b1y; R[2] = b1z;
    R[3] = b2x; R[4] = b2y; R[5] = b2z;
    R[6] = b3x; R[7] = b3y; R[8] = b3z;
}

__device__ inline void compose(const float* Rp, const float* tp,
                               const float* Ri, const float* ti,
                               float* Ro, float* to) {
#pragma unroll
    for (int r = 0; r < 3; r++) {
#pragma unroll
        for (int c = 0; c < 3; c++) {
            Ro[r * 3 + c] = Rp[r * 3 + 0] * Ri[0 * 3 + c] +
                            Rp[r * 3 + 1] * Ri[1 * 3 + c] +
                            Rp[r * 3 + 2] * Ri[2 * 3 + c];
        }
        to[r] = Rp[r * 3 + 0] * ti[0] + Rp[r * 3 + 1] * ti[1] +
                Rp[r * 3 + 2] * ti[2] + tp[r];
    }
}

__global__ void flame_params_kernel(const float* __restrict__ g6,
                                    const float* __restrict__ neck,
                                    const float* __restrict__ jaw,
                                    const float* __restrict__ eye,
                                    const float* __restrict__ jrest,
                                    float* __restrict__ params) {
    int b = blockIdx.x * blockDim.x + threadIdx.x;
    if (b >= Bn) return;

    float R[5][9];
    rot6d(g6 + b * 6, R[0]);
    rodrigues3(neck[b * 3 + 0], neck[b * 3 + 1], neck[b * 3 + 2], R[1]);
    rodrigues3(jaw[b * 3 + 0], jaw[b * 3 + 1], jaw[b * 3 + 2], R[2]);
    rodrigues3(eye[b * 6 + 0], eye[b * 6 + 1], eye[b * 6 + 2], R[3]);
    rodrigues3(eye[b * 6 + 3], eye[b * 6 + 4], eye[b * 6 + 5], R[4]);

    float j[5][3];
#pragma unroll
    for (int i = 0; i < 5; i++) {
        j[i][0] = jrest[b * 15 + i * 3 + 0];
        j[i][1] = jrest[b * 15 + i * 3 + 1];
        j[i][2] = jrest[b * 15 + i * 3 + 2];
    }
    float rel[5][3];
#pragma unroll
    for (int c = 0; c < 3; c++) {
        rel[0][c] = j[0][c];
        rel[1][c] = j[1][c] - j[0][c];
        rel[2][c] = j[2][c] - j[1][c];
        rel[3][c] = j[3][c] - j[1][c];
        rel[4][c] = j[4][c] - j[1][c];
    }

    float CR[5][9], CT[5][3];
#pragma unroll
    for (int i = 0; i < 9; i++) CR[0][i] = R[0][i];
#pragma unroll
    for (int c = 0; c < 3; c++) CT[0][c] = rel[0][c];
    compose(CR[0], CT[0], R[1], rel[1], CR[1], CT[1]);
    compose(CR[1], CT[1], R[2], rel[2], CR[2], CT[2]);
    compose(CR[1], CT[1], R[3], rel[3], CR[3], CT[3]);
    compose(CR[1], CT[1], R[4], rel[4], CR[4], CT[4]);

    float* P = params + b * PARAM_STRIDE;
#pragma unroll
    for (int jj = 0; jj < 4; jj++)
#pragma unroll
        for (int r = 0; r < 3; r++)
#pragma unroll
            for (int c = 0; c < 3; c++)
                P[jj * 9 + r * 3 + c] = R[jj + 1][r * 3 + c] - (r == c ? 1.f : 0.f);
#pragma unroll
    for (int i = 0; i < 5; i++) {
#pragma unroll
        for (int r = 0; r < 3; r++) {
            float t = CT[i][r] - (CR[i][r * 3 + 0] * j[i][0] +
                                  CR[i][r * 3 + 1] * j[i][1] +
                                  CR[i][r * 3 + 2] * j[i][2]);
            P[36 + i * 12 + r * 4 + 0] = CR[i][r * 3 + 0];
            P[36 + i * 12 + r * 4 + 1] = CR[i][r * 3 + 1];
            P[36 + i * 12 + r * 4 + 2] = CR[i][r * 3 + 2];
            P[36 + i * 12 + r * 4 + 3] = t;
        }
    }
}

// ---------------------------------------------------------------------------
// Kernel B: posedirs group (12 floats) loaded ONCE per thread per group,
// PINNED into VGPRs via empty asm so the compiler cannot sink/remat the
// loads into the batch loop (the R1/R2 failure: 2.2 GB of L2 pd re-reads).
// Batches inner (NB=16), accumulators seeded from v_shaped. Per-batch
// params via wave-uniform address -> s_load (scalar pipe).
// ---------------------------------------------------------------------------
__global__ __launch_bounds__(256) void flame_main_kernel(
    const float* __restrict__ vsh, const float* __restrict__ lbs,
    const float* __restrict__ pdirs, const float* __restrict__ params,
    float* __restrict__ out) {
    int v = blockIdx.x * 256 + threadIdx.x;
    bool valid = v < Vn;
    int vc = valid ? v : (Vn - 1);
    int b0 = blockIdx.y * NB;

    float ax[NB], ay[NB], az[NB];
#pragma unroll
    for (int bi = 0; bi < NB; bi++) {
        size_t base = ((size_t)(b0 + bi) * Vn + vc) * 3;
        ax[bi] = vsh[base + 0];
        ay[bi] = vsh[base + 1];
        az[bi] = vsh[base + 2];
    }

    float w[5];
#pragma unroll
    for (int jj = 0; jj < 5; jj++) w[jj] = lbs[(size_t)vc * 5 + jj];

    const float* __restrict__ pv = pdirs + (size_t)vc * 108;

    float cur[12], nxt[12];
    {
        float4 t0 = *reinterpret_cast<const float4*>(pv + 0);
        float4 t1 = *reinterpret_cast<const float4*>(pv + 4);
        float4 t2 = *reinterpret_cast<const float4*>(pv + 8);
        cur[0] = t0.x; cur[1] = t0.y; cur[2] = t0.z; cur[3] = t0.w;
        cur[4] = t1.x; cur[5] = t1.y; cur[6] = t1.z; cur[7] = t1.w;
        cur[8] = t2.x; cur[9] = t2.y; cur[10] = t2.z; cur[11] = t2.w;
#pragma unroll
        for (int i = 0; i < 12; i++) PIN(cur[i]);
    }

#pragma unroll 1
    for (int g = 0; g < 9; g++) {
        if (g < 8) {
            float4 t0 = *reinterpret_cast<const float4*>(pv + g * 12 + 12);
            float4 t1 = *reinterpret_cast<const float4*>(pv + g * 12 + 16);
            float4 t2 = *reinterpret_cast<const float4*>(pv + g * 12 + 20);
            nxt[0] = t0.x; nxt[1] = t0.y; nxt[2] = t0.z; nxt[3] = t0.w;
            nxt[4] = t1.x; nxt[5] = t1.y; nxt[6] = t1.z; nxt[7] = t1.w;
            nxt[8] = t2.x; nxt[9] = t2.y; nxt[10] = t2.z; nxt[11] = t2.w;
#pragma unroll
            for (int i = 0; i < 12; i++) PIN(nxt[i]);
        }
#pragma unroll
        for (int bi = 0; bi < NB; bi++) {
            const float* __restrict__ P =
                params + (b0 + bi) * PARAM_STRIDE + g * 4;  // uniform -> s_load
#pragma unroll
            for (int k = 0; k < 4; k++) {
                float f = P[k];
                ax[bi] = fmaf(f, cur[k * 3 + 0], ax[bi]);
                ay[bi] = fmaf(f, cur[k * 3 + 1], ay[bi]);
                az[bi] = fmaf(f, cur[k * 3 + 2], az[bi]);
            }
        }
        if (g < 8) {
#pragma unroll
            for (int i = 0; i < 12; i++) cur[i] = nxt[i];
        }
    }

    // LBS phase: A matrices via wave-uniform s_load, 3 dword stores/batch.
#pragma unroll
    for (int bi = 0; bi < NB; bi++) {
        const float* __restrict__ A = params + (b0 + bi) * PARAM_STRIDE + 36;
        float x = ax[bi], y = ay[bi], z = az[bi];
        float ox = 0.f, oy = 0.f, oz = 0.f;
#pragma unroll
        for (int jj = 0; jj < 5; jj++) {
            const float* Aj = A + jj * 12;
            float wj = w[jj];
            float rx = fmaf(Aj[0], x, fmaf(Aj[1], y, fmaf(Aj[2], z, Aj[3])));
            float ry = fmaf(Aj[4], x, fmaf(Aj[5], y, fmaf(Aj[6], z, Aj[7])));
            float rz = fmaf(Aj[8], x, fmaf(Aj[9], y, fmaf(Aj[10], z, Aj[11])));
            ox = fmaf(wj, rx, ox);
            oy = fmaf(wj, ry, oy);
            oz = fmaf(wj, rz, oz);
        }
        if (valid) {
            size_t base = ((size_t)(b0 + bi) * Vn + vc) * 3;
            out[base + 0] = ox;
            out[base + 1] = oy;
            out[base + 2] = oz;
        }
    }
}

extern "C" void kernel_launch(void* const* d_in, const int* in_sizes, int n_in,
                              void* d_out, int out_size, void* d_ws, size_t ws_size,
                              hipStream_t stream) {
    const float* vsh   = (const float*)d_in[0];
    const float* g6    = (const float*)d_in[1];
    const float* neck  = (const float*)d_in[2];
    const float* jaw   = (const float*)d_in[3];
    const float* eye   = (const float*)d_in[4];
    const float* jrest = (const float*)d_in[5];
    const float* lbs   = (const float*)d_in[6];
    const float* pdirs = (const float*)d_in[7];
    float* out = (float*)d_out;
    float* params = (float*)d_ws;  // Bn * 96 floats = 384 KB

    hipLaunchKernelGGL(flame_params_kernel, dim3((Bn + 255) / 256), dim3(256), 0,
                       stream, g6, neck, jaw, eye, jrest, params);

    dim3 grid((Vn + 255) / 256, Bn / NB);
    hipLaunchKernelGGL(flame_main_kernel, grid, dim3(256), 0, stream, vsh, lbs,
                       pdirs, params, out);
}

// Round 4
// 59.105 us; speedup vs baseline: 1.2506x; 1.2506x over previous
//
#include <hip/hip_runtime.h>
#include <math.h>

constexpr int Bn = 1024, Vn = 5023;
constexpr int NB = 8;             // batches per block in the main kernel
constexpr int PARAM_STRIDE = 96;  // 36 pose_feat + 5*12 A per batch (floats)

// Pin a float in a VGPR so the producing load cannot be sunk/rematerialized.
#define PIN(x) asm volatile("" : "+v"(x))

// ---------------------------------------------------------------------------
// Kernel A: per-batch pose math. 1 thread per batch.
// params layout per batch: [0..35] pose_feat (joint-1..4, row-major 3x3 - I),
//                          [36..95] A_j as 3x4 row-major, j=0..4
// ---------------------------------------------------------------------------

__device__ inline void rodrigues3(float rx, float ry, float rz, float R[9]) {
    const float eps = 1e-8f;
    float ax = rx + eps, ay = ry + eps, az = rz + eps;
    float ang = sqrtf(ax * ax + ay * ay + az * az);
    float inv = 1.0f / ang;
    float dx = rx * inv, dy = ry * inv, dz = rz * inv;
    float s = sinf(ang), c = cosf(ang), omc = 1.0f - c;
    float K[9] = {0.f, -dz, dy, dz, 0.f, -dx, -dy, dx, 0.f};
    float K2[9];
#pragma unroll
    for (int r = 0; r < 3; r++)
#pragma unroll
        for (int k = 0; k < 3; k++) {
            float acc = 0.f;
#pragma unroll
            for (int i = 0; i < 3; i++) acc += K[r * 3 + i] * K[i * 3 + k];
            K2[r * 3 + k] = acc;
        }
#pragma unroll
    for (int i = 0; i < 9; i++) R[i] = s * K[i] + omc * K2[i];
    R[0] += 1.f; R[4] += 1.f; R[8] += 1.f;
}

__device__ inline void rot6d(const float* x, float R[9]) {
    float a1x = x[0], a1y = x[1], a1z = x[2];
    float a2x = x[3], a2y = x[4], a2z = x[5];
    float n1 = sqrtf(a1x * a1x + a1y * a1y + a1z * a1z);
    float b1x = a1x / n1, b1y = a1y / n1, b1z = a1z / n1;
    float d = b1x * a2x + b1y * a2y + b1z * a2z;
    float tx = a2x - d * b1x, ty = a2y - d * b1y, tz = a2z - d * b1z;
    float n2 = sqrtf(tx * tx + ty * ty + tz * tz);
    float b2x = tx / n2, b2y = ty / n2, b2z = tz / n2;
    float b3x = b1y * b2z - b1z * b2y;
    float b3y = b1z * b2x - b1x * b2z;
    float b3z = b1x * b2y - b1y * b2x;
    R[0] = b1x; R[1] = b1y; R[2] = b1z;
    R[3] = b2x; R[4] = b2y; R[5] = b2z;
    R[6] = b3x; R[7] = b3y; R[8] = b3z;
}

__device__ inline void compose(const float* Rp, const float* tp,
                               const float* Ri, const float* ti,
                               float* Ro, float* to) {
#pragma unroll
    for (int r = 0; r < 3; r++) {
#pragma unroll
        for (int c = 0; c < 3; c++) {
            Ro[r * 3 + c] = Rp[r * 3 + 0] * Ri[0 * 3 + c] +
                            Rp[r * 3 + 1] * Ri[1 * 3 + c] +
                            Rp[r * 3 + 2] * Ri[2 * 3 + c];
        }
        to[r] = Rp[r * 3 + 0] * ti[0] + Rp[r * 3 + 1] * ti[1] +
                Rp[r * 3 + 2] * ti[2] + tp[r];
    }
}

__global__ void flame_params_kernel(const float* __restrict__ g6,
                                    const float* __restrict__ neck,
                                    const float* __restrict__ jaw,
                                    const float* __restrict__ eye,
                                    const float* __restrict__ jrest,
                                    float* __restrict__ params) {
    int b = blockIdx.x * blockDim.x + threadIdx.x;
    if (b >= Bn) return;

    float R[5][9];
    rot6d(g6 + b * 6, R[0]);
    rodrigues3(neck[b * 3 + 0], neck[b * 3 + 1], neck[b * 3 + 2], R[1]);
    rodrigues3(jaw[b * 3 + 0], jaw[b * 3 + 1], jaw[b * 3 + 2], R[2]);
    rodrigues3(eye[b * 6 + 0], eye[b * 6 + 1], eye[b * 6 + 2], R[3]);
    rodrigues3(eye[b * 6 + 3], eye[b * 6 + 4], eye[b * 6 + 5], R[4]);

    float j[5][3];
#pragma unroll
    for (int i = 0; i < 5; i++) {
        j[i][0] = jrest[b * 15 + i * 3 + 0];
        j[i][1] = jrest[b * 15 + i * 3 + 1];
        j[i][2] = jrest[b * 15 + i * 3 + 2];
    }
    float rel[5][3];
#pragma unroll
    for (int c = 0; c < 3; c++) {
        rel[0][c] = j[0][c];
        rel[1][c] = j[1][c] - j[0][c];
        rel[2][c] = j[2][c] - j[1][c];
        rel[3][c] = j[3][c] - j[1][c];
        rel[4][c] = j[4][c] - j[1][c];
    }

    float CR[5][9], CT[5][3];
#pragma unroll
    for (int i = 0; i < 9; i++) CR[0][i] = R[0][i];
#pragma unroll
    for (int c = 0; c < 3; c++) CT[0][c] = rel[0][c];
    compose(CR[0], CT[0], R[1], rel[1], CR[1], CT[1]);
    compose(CR[1], CT[1], R[2], rel[2], CR[2], CT[2]);
    compose(CR[1], CT[1], R[3], rel[3], CR[3], CT[3]);
    compose(CR[1], CT[1], R[4], rel[4], CR[4], CT[4]);

    float* P = params + b * PARAM_STRIDE;
#pragma unroll
    for (int jj = 0; jj < 4; jj++)
#pragma unroll
        for (int r = 0; r < 3; r++)
#pragma unroll
            for (int c = 0; c < 3; c++)
                P[jj * 9 + r * 3 + c] = R[jj + 1][r * 3 + c] - (r == c ? 1.f : 0.f);
#pragma unroll
    for (int i = 0; i < 5; i++) {
#pragma unroll
        for (int r = 0; r < 3; r++) {
            float t = CT[i][r] - (CR[i][r * 3 + 0] * j[i][0] +
                                  CR[i][r * 3 + 1] * j[i][1] +
                                  CR[i][r * 3 + 2] * j[i][2]);
            P[36 + i * 12 + r * 4 + 0] = CR[i][r * 3 + 0];
            P[36 + i * 12 + r * 4 + 1] = CR[i][r * 3 + 1];
            P[36 + i * 12 + r * 4 + 2] = CR[i][r * 3 + 2];
            P[36 + i * 12 + r * 4 + 3] = t;
        }
    }
}

// ---------------------------------------------------------------------------
// Kernel B. Diagnosis from R1-R3: per-batch params were per-lane scalar
// global_load_dword broadcasts (~96 VMEM instrs per wave-batch) -> the kernel
// was VMEM-ISSUE bound (~50us of issue), not BW/VALU bound. Fix: every param
// read is a float4 (4x fewer VMEM instrs), pd stays a pinned 12-float window,
// NB=8 + small register footprint for the 8-waves/SIMD occupancy bucket.
// ---------------------------------------------------------------------------
__global__ __launch_bounds__(256) void flame_main_kernel(
    const float* __restrict__ vsh, const float* __restrict__ lbs,
    const float* __restrict__ pdirs, const float* __restrict__ params,
    float* __restrict__ out) {
    int v = blockIdx.x * 256 + threadIdx.x;
    bool valid = v < Vn;
    int vc = valid ? v : (Vn - 1);
    int b0 = blockIdx.y * NB;

    // Seed accumulators from v_shaped: 24 independent coalesced loads.
    float ax[NB], ay[NB], az[NB];
#pragma unroll
    for (int bi = 0; bi < NB; bi++) {
        size_t base = ((size_t)(b0 + bi) * Vn + vc) * 3;
        ax[bi] = vsh[base + 0];
        ay[bi] = vsh[base + 1];
        az[bi] = vsh[base + 2];
    }

    float w[5];
#pragma unroll
    for (int jj = 0; jj < 5; jj++) w[jj] = lbs[(size_t)vc * 5 + jj];

    const float* __restrict__ pv = pdirs + (size_t)vc * 108;

    // Pose blendshape phase: g = group of 4 pose_feat coords.
#pragma unroll 1
    for (int g = 0; g < 9; g++) {
        float4 t0 = *reinterpret_cast<const float4*>(pv + g * 12 + 0);
        float4 t1 = *reinterpret_cast<const float4*>(pv + g * 12 + 4);
        float4 t2 = *reinterpret_cast<const float4*>(pv + g * 12 + 8);
        float pd0 = t0.x, pd1 = t0.y, pd2 = t0.z, pd3 = t0.w;
        float pd4 = t1.x, pd5 = t1.y, pd6 = t1.z, pd7 = t1.w;
        float pd8 = t2.x, pd9 = t2.y, pd10 = t2.z, pd11 = t2.w;
        PIN(pd0); PIN(pd1); PIN(pd2); PIN(pd3);
        PIN(pd4); PIN(pd5); PIN(pd6); PIN(pd7);
        PIN(pd8); PIN(pd9); PIN(pd10); PIN(pd11);

        // 2-deep pipeline on the per-batch pose_feat float4.
        float4 fc = *(reinterpret_cast<const float4*>(
                          params + (size_t)b0 * PARAM_STRIDE) + g);
#pragma unroll
        for (int bi = 0; bi < NB; bi++) {
            float4 fn = fc;
            if (bi + 1 < NB)
                fn = *(reinterpret_cast<const float4*>(
                           params + (size_t)(b0 + bi + 1) * PARAM_STRIDE) + g);
            ax[bi] = fmaf(fc.x, pd0, ax[bi]);
            ay[bi] = fmaf(fc.x, pd1, ay[bi]);
            az[bi] = fmaf(fc.x, pd2, az[bi]);
            ax[bi] = fmaf(fc.y, pd3, ax[bi]);
            ay[bi] = fmaf(fc.y, pd4, ay[bi]);
            az[bi] = fmaf(fc.y, pd5, az[bi]);
            ax[bi] = fmaf(fc.z, pd6, ax[bi]);
            ay[bi] = fmaf(fc.z, pd7, ay[bi]);
            az[bi] = fmaf(fc.z, pd8, az[bi]);
            ax[bi] = fmaf(fc.w, pd9, ax[bi]);
            ay[bi] = fmaf(fc.w, pd10, ay[bi]);
            az[bi] = fmaf(fc.w, pd11, az[bi]);
            fc = fn;
        }
    }

    // LBS phase: A matrices as 3 float4 per joint (aligned: 36+12j floats).
#pragma unroll 1
    for (int bi = 0; bi < NB; bi++) {
        const float4* __restrict__ A4 = reinterpret_cast<const float4*>(
            params + (size_t)(b0 + bi) * PARAM_STRIDE + 36);
        float x = ax[bi], y = ay[bi], z = az[bi];
        float ox = 0.f, oy = 0.f, oz = 0.f;
#pragma unroll
        for (int jj = 0; jj < 5; jj++) {
            float4 r0 = A4[jj * 3 + 0];
            float4 r1 = A4[jj * 3 + 1];
            float4 r2 = A4[jj * 3 + 2];
            float wj = w[jj];
            float rx = fmaf(r0.x, x, fmaf(r0.y, y, fmaf(r0.z, z, r0.w)));
            float ry = fmaf(r1.x, x, fmaf(r1.y, y, fmaf(r1.z, z, r1.w)));
            float rz = fmaf(r2.x, x, fmaf(r2.y, y, fmaf(r2.z, z, r2.w)));
            ox = fmaf(wj, rx, ox);
            oy = fmaf(wj, ry, oy);
            oz = fmaf(wj, rz, oz);
        }
        if (valid) {
            size_t base = ((size_t)(b0 + bi) * Vn + vc) * 3;
            out[base + 0] = ox;
            out[base + 1] = oy;
            out[base + 2] = oz;
        }
    }
}

extern "C" void kernel_launch(void* const* d_in, const int* in_sizes, int n_in,
                              void* d_out, int out_size, void* d_ws, size_t ws_size,
                              hipStream_t stream) {
    const float* vsh   = (const float*)d_in[0];
    const float* g6    = (const float*)d_in[1];
    const float* neck  = (const float*)d_in[2];
    const float* jaw   = (const float*)d_in[3];
    const float* eye   = (const float*)d_in[4];
    const float* jrest = (const float*)d_in[5];
    const float* lbs   = (const float*)d_in[6];
    const float* pdirs = (const float*)d_in[7];
    float* out = (float*)d_out;
    float* params = (float*)d_ws;  // Bn * 96 floats = 384 KB

    hipLaunchKernelGGL(flame_params_kernel, dim3((Bn + 255) / 256), dim3(256), 0,
                       stream, g6, neck, jaw, eye, jrest, params);

    dim3 grid((Vn + 255) / 256, Bn / NB);
    hipLaunchKernelGGL(flame_main_kernel, grid, dim3(256), 0, stream, vsh, lbs,
                       pdirs, params, out);
}

// Round 5
// 55.250 us; speedup vs baseline: 1.3379x; 1.0698x over previous
//
#include <hip/hip_runtime.h>
#include <math.h>

constexpr int Bn = 1024, Vn = 5023;
constexpr int NB = 16;            // batches per block in the main kernel
constexpr int PARAM_STRIDE = 96;  // 36 pose_feat + 5*12 A per batch (floats)

// Pin a float in a VGPR so the producing load cannot be sunk/rematerialized.
#define PIN(x) asm volatile("" : "+v"(x))

// ---------------------------------------------------------------------------
// Kernel A: per-batch pose math. 1 thread per batch.
// params layout per batch: [0..35] pose_feat (joint-1..4, row-major 3x3 - I),
//                          [36..95] A_j as 3x4 row-major, j=0..4
// ---------------------------------------------------------------------------

__device__ inline void rodrigues3(float rx, float ry, float rz, float R[9]) {
    const float eps = 1e-8f;
    float ax = rx + eps, ay = ry + eps, az = rz + eps;
    float ang = sqrtf(ax * ax + ay * ay + az * az);
    float inv = 1.0f / ang;
    float dx = rx * inv, dy = ry * inv, dz = rz * inv;
    float s = sinf(ang), c = cosf(ang), omc = 1.0f - c;
    float K[9] = {0.f, -dz, dy, dz, 0.f, -dx, -dy, dx, 0.f};
    float K2[9];
#pragma unroll
    for (int r = 0; r < 3; r++)
#pragma unroll
        for (int k = 0; k < 3; k++) {
            float acc = 0.f;
#pragma unroll
            for (int i = 0; i < 3; i++) acc += K[r * 3 + i] * K[i * 3 + k];
            K2[r * 3 + k] = acc;
        }
#pragma unroll
    for (int i = 0; i < 9; i++) R[i] = s * K[i] + omc * K2[i];
    R[0] += 1.f; R[4] += 1.f; R[8] += 1.f;
}

__device__ inline void rot6d(const float* x, float R[9]) {
    float a1x = x[0], a1y = x[1], a1z = x[2];
    float a2x = x[3], a2y = x[4], a2z = x[5];
    float n1 = sqrtf(a1x * a1x + a1y * a1y + a1z * a1z);
    float b1x = a1x / n1, b1y = a1y / n1, b1z = a1z / n1;
    float d = b1x * a2x + b1y * a2y + b1z * a2z;
    float tx = a2x - d * b1x, ty = a2y - d * b1y, tz = a2z - d * b1z;
    float n2 = sqrtf(tx * tx + ty * ty + tz * tz);
    float b2x = tx / n2, b2y = ty / n2, b2z = tz / n2;
    float b3x = b1y * b2z - b1z * b2y;
    float b3y = b1z * b2x - b1x * b2z;
    float b3z = b1x * b2y - b1y * b2x;
    R[0] = b1x; R[1] = b1y; R[2] = b1z;
    R[3] = b2x; R[4] = b2y; R[5] = b2z;
    R[6] = b3x; R[7] = b3y; R[8] = b3z;
}

__device__ inline void compose(const float* Rp, const float* tp,
                               const float* Ri, const float* ti,
                               float* Ro, float* to) {
#pragma unroll
    for (int r = 0; r < 3; r++) {
#pragma unroll
        for (int c = 0; c < 3; c++) {
            Ro[r * 3 + c] = Rp[r * 3 + 0] * Ri[0 * 3 + c] +
                            Rp[r * 3 + 1] * Ri[1 * 3 + c] +
                            Rp[r * 3 + 2] * Ri[2 * 3 + c];
        }
        to[r] = Rp[r * 3 + 0] * ti[0] + Rp[r * 3 + 1] * ti[1] +
                Rp[r * 3 + 2] * ti[2] + tp[r];
    }
}

__global__ void flame_params_kernel(const float* __restrict__ g6,
                                    const float* __restrict__ neck,
                                    const float* __restrict__ jaw,
                                    const float* __restrict__ eye,
                                    const float* __restrict__ jrest,
                                    float* __restrict__ params) {
    int b = blockIdx.x * blockDim.x + threadIdx.x;
    if (b >= Bn) return;

    float R[5][9];
    rot6d(g6 + b * 6, R[0]);
    rodrigues3(neck[b * 3 + 0], neck[b * 3 + 1], neck[b * 3 + 2], R[1]);
    rodrigues3(jaw[b * 3 + 0], jaw[b * 3 + 1], jaw[b * 3 + 2], R[2]);
    rodrigues3(eye[b * 6 + 0], eye[b * 6 + 1], eye[b * 6 + 2], R[3]);
    rodrigues3(eye[b * 6 + 3], eye[b * 6 + 4], eye[b * 6 + 5], R[4]);

    float j[5][3];
#pragma unroll
    for (int i = 0; i < 5; i++) {
        j[i][0] = jrest[b * 15 + i * 3 + 0];
        j[i][1] = jrest[b * 15 + i * 3 + 1];
        j[i][2] = jrest[b * 15 + i * 3 + 2];
    }
    float rel[5][3];
#pragma unroll
    for (int c = 0; c < 3; c++) {
        rel[0][c] = j[0][c];
        rel[1][c] = j[1][c] - j[0][c];
        rel[2][c] = j[2][c] - j[1][c];
        rel[3][c] = j[3][c] - j[1][c];
        rel[4][c] = j[4][c] - j[1][c];
    }

    float CR[5][9], CT[5][3];
#pragma unroll
    for (int i = 0; i < 9; i++) CR[0][i] = R[0][i];
#pragma unroll
    for (int c = 0; c < 3; c++) CT[0][c] = rel[0][c];
    compose(CR[0], CT[0], R[1], rel[1], CR[1], CT[1]);
    compose(CR[1], CT[1], R[2], rel[2], CR[2], CT[2]);
    compose(CR[1], CT[1], R[3], rel[3], CR[3], CT[3]);
    compose(CR[1], CT[1], R[4], rel[4], CR[4], CT[4]);

    float* P = params + b * PARAM_STRIDE;
#pragma unroll
    for (int jj = 0; jj < 4; jj++)
#pragma unroll
        for (int r = 0; r < 3; r++)
#pragma unroll
            for (int c = 0; c < 3; c++)
                P[jj * 9 + r * 3 + c] = R[jj + 1][r * 3 + c] - (r == c ? 1.f : 0.f);
#pragma unroll
    for (int i = 0; i < 5; i++) {
#pragma unroll
        for (int r = 0; r < 3; r++) {
            float t = CT[i][r] - (CR[i][r * 3 + 0] * j[i][0] +
                                  CR[i][r * 3 + 1] * j[i][1] +
                                  CR[i][r * 3 + 2] * j[i][2]);
            P[36 + i * 12 + r * 4 + 0] = CR[i][r * 3 + 0];
            P[36 + i * 12 + r * 4 + 1] = CR[i][r * 3 + 1];
            P[36 + i * 12 + r * 4 + 2] = CR[i][r * 3 + 2];
            P[36 + i * 12 + r * 4 + 3] = t;
        }
    }
}

// ---------------------------------------------------------------------------
// Kernel B. R1-R4 lesson: the limiter is memory-level parallelism, not
// traffic (R1's brute-force L2 stream at 53us beat every "optimized" low-MLP
// version). Here: the FULL 108-float posedirs row is loaded as 27 concurrent
// dwordx4 (27.6 KB/wave in flight) and PINNED in VGPRs for the whole batch
// loop (~160 VGPR, __launch_bounds__(256,3) -> 12 waves/CU). The batch loop
// is rolled (unroll 2) with NO serializing pins: each batch's 25 loads
// (9 pose f4 + vsh float3 + 15 A f4, L1-resident broadcasts) issue as an
// independent burst overlapped with the neighbor iteration's ~170 FMAs.
// ---------------------------------------------------------------------------
__global__ __launch_bounds__(256, 3) void flame_main_kernel(
    const float* __restrict__ vsh, const float* __restrict__ lbs,
    const float* __restrict__ pdirs, const float* __restrict__ params,
    float* __restrict__ out) {
    int v = blockIdx.x * 256 + threadIdx.x;
    bool valid = v < Vn;
    int vc = valid ? v : (Vn - 1);
    int b0 = blockIdx.y * NB;

    // ---- load entire posedirs row: 27 independent dwordx4, then pin ----
    const float* __restrict__ pv = pdirs + (size_t)vc * 108;
    float pd[108];
#pragma unroll
    for (int i = 0; i < 27; i++) {
        float4 t = *reinterpret_cast<const float4*>(pv + i * 4);
        pd[i * 4 + 0] = t.x;
        pd[i * 4 + 1] = t.y;
        pd[i * 4 + 2] = t.z;
        pd[i * 4 + 3] = t.w;
    }
#pragma unroll
    for (int i = 0; i < 108; i++) PIN(pd[i]);

    float w[5];
#pragma unroll
    for (int jj = 0; jj < 5; jj++) w[jj] = lbs[(size_t)vc * 5 + jj];

#pragma unroll 2
    for (int bi = 0; bi < NB; bi++) {
        int b = b0 + bi;
        const float4* __restrict__ P4 =
            reinterpret_cast<const float4*>(params + (size_t)b * PARAM_STRIDE);
        size_t base = ((size_t)b * Vn + vc) * 3;

        // vsh load issues first; latency hidden under the 108-FMA pose chain.
        float3 vs = *reinterpret_cast<const float3*>(vsh + base);

        // pose blendshape: 9 broadcast float4 (L1-hot), 108 FMA
        float px = 0.f, py = 0.f, pz = 0.f;
#pragma unroll
        for (int g = 0; g < 9; g++) {
            float4 f = P4[g];
            px = fmaf(f.x, pd[g * 12 + 0], px);
            py = fmaf(f.x, pd[g * 12 + 1], py);
            pz = fmaf(f.x, pd[g * 12 + 2], pz);
            px = fmaf(f.y, pd[g * 12 + 3], px);
            py = fmaf(f.y, pd[g * 12 + 4], py);
            pz = fmaf(f.y, pd[g * 12 + 5], pz);
            px = fmaf(f.z, pd[g * 12 + 6], px);
            py = fmaf(f.z, pd[g * 12 + 7], py);
            pz = fmaf(f.z, pd[g * 12 + 8], pz);
            px = fmaf(f.w, pd[g * 12 + 9], px);
            py = fmaf(f.w, pd[g * 12 + 10], py);
            pz = fmaf(f.w, pd[g * 12 + 11], pz);
        }

        float x = vs.x + px, y = vs.y + py, z = vs.z + pz;

        // LBS: 15 broadcast float4 (L1-hot), 60 FMA
        float ox = 0.f, oy = 0.f, oz = 0.f;
#pragma unroll
        for (int jj = 0; jj < 5; jj++) {
            float4 r0 = P4[9 + jj * 3 + 0];
            float4 r1 = P4[9 + jj * 3 + 1];
            float4 r2 = P4[9 + jj * 3 + 2];
            float wj = w[jj];
            float rx = fmaf(r0.x, x, fmaf(r0.y, y, fmaf(r0.z, z, r0.w)));
            float ry = fmaf(r1.x, x, fmaf(r1.y, y, fmaf(r1.z, z, r1.w)));
            float rz = fmaf(r2.x, x, fmaf(r2.y, y, fmaf(r2.z, z, r2.w)));
            ox = fmaf(wj, rx, ox);
            oy = fmaf(wj, ry, oy);
            oz = fmaf(wj, rz, oz);
        }
        if (valid) {
            float3 o;
            o.x = ox; o.y = oy; o.z = oz;
            *reinterpret_cast<float3*>(out + base) = o;
        }
    }
}

extern "C" void kernel_launch(void* const* d_in, const int* in_sizes, int n_in,
                              void* d_out, int out_size, void* d_ws, size_t ws_size,
                              hipStream_t stream) {
    const float* vsh   = (const float*)d_in[0];
    const float* g6    = (const float*)d_in[1];
    const float* neck  = (const float*)d_in[2];
    const float* jaw   = (const float*)d_in[3];
    const float* eye   = (const float*)d_in[4];
    const float* jrest = (const float*)d_in[5];
    const float* lbs   = (const float*)d_in[6];
    const float* pdirs = (const float*)d_in[7];
    float* out = (float*)d_out;
    float* params = (float*)d_ws;  // Bn * 96 floats = 384 KB

    hipLaunchKernelGGL(flame_params_kernel, dim3((Bn + 255) / 256), dim3(256), 0,
                       stream, g6, neck, jaw, eye, jrest, params);

    dim3 grid((Vn + 255) / 256, Bn / NB);
    hipLaunchKernelGGL(flame_main_kernel, grid, dim3(256), 0, stream, vsh, lbs,
                       pdirs, params, out);
}